// Round 2
// baseline (19705.133 us; speedup 1.0000x reference)
//
#include <hip/hip_runtime.h>
#include <math.h>

#define S_LEN 64
#define T_LEN 48
#define B_SZ  32
#define NV    32000
#define E_DIM 256
#define H_DIM 512
#define D_DIM 512
#define H2    1024          // 2H
#define G3H   1536          // 3H == 3D
#define KDEC  1280          // E + 2H
#define KPRED 1792          // D + 2H + E

__device__ __forceinline__ float sigmoidf_(float x){ return 1.0f/(1.0f + expf(-x)); }

// ---------- encoder embedding gather: emb_src[s][b][e] = enc_emb[src[s][b]][e]
__global__ void k_embed(const int* __restrict__ src, const float* __restrict__ enc_emb,
                        float* __restrict__ emb_src){
    int idx = blockIdx.x*256 + threadIdx.x;   // float4 index; total S*B*E/4 = 131072
    int e4 = idx & 63;                        // E/4
    int r  = idx >> 6;                        // s*B + b
    int tok = src[r];
    ((float4*)emb_src)[idx] = ((const float4*)(enc_emb + (long)tok*E_DIM))[e4];
}

// ---------- generic 64x64 tiled fp32 GEMM.  C[M,N] = A[M,K] @ op(W) + bias[N]
// BT=1: W is (N,K) row-major (NT).  BT=0: W is (K,N) row-major (NN).
// Requires M%64==0, N%64==0, K%16==0.
template<int BT>
__global__ void __launch_bounds__(256) k_gemm64(const float* __restrict__ A,
        const float* __restrict__ W, const float* __restrict__ bias,
        float* __restrict__ C, int M, int N, int K){
    __shared__ float As[16][64];
    __shared__ float Bs[16][64];
    int ntile = N >> 6;
    int m0 = (blockIdx.x / ntile) << 6;
    int n0 = (blockIdx.x % ntile) << 6;
    int tid = threadIdx.x;
    int tm = tid >> 4, tn = tid & 15;
    float acc[4][4] = {{0}};
    for (int k0 = 0; k0 < K; k0 += 16){
        __syncthreads();
        {   // A tile: 64 rows x 16 k, stored transposed
            int row = tid >> 2, kq = (tid & 3) << 2;
            float4 v = *(const float4*)(A + (long)(m0+row)*K + k0 + kq);
            As[kq+0][row]=v.x; As[kq+1][row]=v.y; As[kq+2][row]=v.z; As[kq+3][row]=v.w;
        }
        if (BT){
            int row = tid >> 2, kq = (tid & 3) << 2;
            float4 v = *(const float4*)(W + (long)(n0+row)*K + k0 + kq);
            Bs[kq+0][row]=v.x; Bs[kq+1][row]=v.y; Bs[kq+2][row]=v.z; Bs[kq+3][row]=v.w;
        } else {
            int kk = tid >> 4, nq = (tid & 15) << 2;
            *(float4*)&Bs[kk][nq] = *(const float4*)(W + (long)(k0+kk)*N + n0 + nq);
        }
        __syncthreads();
        #pragma unroll
        for (int k = 0; k < 16; ++k){
            float4 a4 = ((const float4*)As[k])[tm];
            float4 b4 = ((const float4*)Bs[k])[tn];
            float av[4] = {a4.x,a4.y,a4.z,a4.w};
            float bv[4] = {b4.x,b4.y,b4.z,b4.w};
            #pragma unroll
            for (int i=0;i<4;++i)
                #pragma unroll
                for (int j=0;j<4;++j)
                    acc[i][j] += av[i]*bv[j];
        }
    }
    int n = n0 + (tn<<2);
    float b0=bias[n], b1=bias[n+1], b2=bias[n+2], b3=bias[n+3];
    #pragma unroll
    for (int i=0;i<4;++i){
        int m = m0 + (tm<<2) + i;
        float4 o = make_float4(acc[i][0]+b0, acc[i][1]+b1, acc[i][2]+b2, acc[i][3]+b3);
        *(float4*)(C + (long)m*N + n) = o;
    }
}

// ---------- one encoder timestep, both directions fused.
// blocks 0..31: forward (16 j each); blocks 32..63: backward.
__global__ void __launch_bounds__(256) k_enc_step(int t,
        const float* __restrict__ gi_f, const float* __restrict__ gi_b,
        const float* __restrict__ Whh_f, const float* __restrict__ Whh_b,
        const float* __restrict__ bhh_f, const float* __restrict__ bhh_b,
        float* __restrict__ outs_f, float* __restrict__ outs_b){
    __shared__ float ch[32*128];
    int dir  = blockIdx.x >> 5;
    int jblk = blockIdx.x & 31;
    int j0 = jblk << 4;
    int tid = threadIdx.x;
    int b = tid & 31, jj = tid >> 5;
    const float* gi   = dir ? gi_b  : gi_f;
    const float* Whh  = dir ? Whh_b : Whh_f;
    const float* bhh  = dir ? bhh_b : bhh_f;
    float*       outs = dir ? outs_b : outs_f;
    const float* hprev = (t > 0) ? (outs + (long)(t-1)*B_SZ*H_DIM) : nullptr;
    int ja = j0 + jj, jb = j0 + 8 + jj;
    float hr0=0,hz0=0,hn0=0, hr1=0,hz1=0,hn1=0;
    for (int kc = 0; kc < 4; ++kc){
        __syncthreads();
        for (int e = tid; e < 1024; e += 256){
            int bb = e >> 5, kq = (e & 31) << 2;
            float4 v = hprev ? *(const float4*)(hprev + bb*H_DIM + kc*128 + kq)
                             : make_float4(0.f,0.f,0.f,0.f);
            *(float4*)&ch[bb*128 + kq] = v;
        }
        __syncthreads();
        const float* wra = Whh + (long)ja*H_DIM + kc*128;
        const float* wza = Whh + (long)(H_DIM + ja)*H_DIM + kc*128;
        const float* wna = Whh + (long)(2*H_DIM + ja)*H_DIM + kc*128;
        const float* wrb = Whh + (long)jb*H_DIM + kc*128;
        const float* wzb = Whh + (long)(H_DIM + jb)*H_DIM + kc*128;
        const float* wnb = Whh + (long)(2*H_DIM + jb)*H_DIM + kc*128;
        const float* hrow = &ch[b*128];
        #pragma unroll 8
        for (int kq = 0; kq < 128; kq += 4){
            float4 h4 = *(const float4*)&hrow[kq];
            float4 w;
            w = *(const float4*)&wra[kq]; hr0 += h4.x*w.x+h4.y*w.y+h4.z*w.z+h4.w*w.w;
            w = *(const float4*)&wza[kq]; hz0 += h4.x*w.x+h4.y*w.y+h4.z*w.z+h4.w*w.w;
            w = *(const float4*)&wna[kq]; hn0 += h4.x*w.x+h4.y*w.y+h4.z*w.z+h4.w*w.w;
            w = *(const float4*)&wrb[kq]; hr1 += h4.x*w.x+h4.y*w.y+h4.z*w.z+h4.w*w.w;
            w = *(const float4*)&wzb[kq]; hz1 += h4.x*w.x+h4.y*w.y+h4.z*w.z+h4.w*w.w;
            w = *(const float4*)&wnb[kq]; hn1 += h4.x*w.x+h4.y*w.y+h4.z*w.z+h4.w*w.w;
        }
    }
    int gidx = dir ? (S_LEN-1-t) : t;
    long gbase = (long)gidx*B_SZ*G3H + (long)b*G3H;
    float* orow = outs + (long)t*B_SZ*H_DIM + (long)b*H_DIM;
    {
        float r = sigmoidf_(gi[gbase + ja] + hr0 + bhh[ja]);
        float z = sigmoidf_(gi[gbase + H_DIM + ja] + hz0 + bhh[H_DIM + ja]);
        float n = tanhf(gi[gbase + 2*H_DIM + ja] + r*(hn0 + bhh[2*H_DIM + ja]));
        float hv = (t>0) ? hprev[b*H_DIM + ja] : 0.f;
        orow[ja] = (1.f - z)*n + z*hv;
    }
    {
        float r = sigmoidf_(gi[gbase + jb] + hr1 + bhh[jb]);
        float z = sigmoidf_(gi[gbase + H_DIM + jb] + hz1 + bhh[H_DIM + jb]);
        float n = tanhf(gi[gbase + 2*H_DIM + jb] + r*(hn1 + bhh[2*H_DIM + jb]));
        float hv = (t>0) ? hprev[b*H_DIM + jb] : 0.f;
        orow[jb] = (1.f - z)*n + z*hv;
    }
}

// ---------- assemble enc_bs[b][s][:] = [outs_f[s][b] | outs_b[S-1-s][b]]
__global__ void k_encbs(const float* __restrict__ outs_f, const float* __restrict__ outs_b,
                        float* __restrict__ enc_bs){
    int idx = blockIdx.x*256 + threadIdx.x;   // float4 index; total B*S*H2/4 = 524288
    int j4 = idx & 255;                       // H2/4
    int r  = idx >> 8;                        // b*S + s
    int s = r & 63, b = r >> 6;
    float4 v;
    if (j4 < 128) v = *(const float4*)(outs_f + ((long)s*B_SZ + b)*H_DIM + (j4<<2));
    else          v = *(const float4*)(outs_b + ((long)(S_LEN-1-s)*B_SZ + b)*H_DIM + ((j4-128)<<2));
    ((float4*)enc_bs)[idx] = v;
}

// ---------- hidden = tanh([h_f|h_b] @ Wfc + bfc); also init inp = trg[0]
__global__ void k_hidden(const float* __restrict__ outs_f, const float* __restrict__ outs_b,
                         const float* __restrict__ Wfc, const float* __restrict__ bfc,
                         const int* __restrict__ trg, float* __restrict__ h0,
                         int* __restrict__ inp){
    int idx = blockIdx.x*256 + threadIdx.x;   // 64 blocks -> 16384 outputs
    int b = idx >> 9, d = idx & 511;
    const float* af = outs_f + (long)(S_LEN-1)*B_SZ*H_DIM + (long)b*H_DIM;
    const float* ab = outs_b + (long)(S_LEN-1)*B_SZ*H_DIM + (long)b*H_DIM;
    float acc = bfc[d];
    for (int k=0;k<H_DIM;k++) acc += af[k]*Wfc[(long)k*D_DIM + d];
    for (int k=0;k<H_DIM;k++) acc += ab[k]*Wfc[(long)(H_DIM+k)*D_DIM + d];
    h0[idx] = tanhf(acc);
    if (idx < B_SZ) inp[idx] = trg[idx];
}

// ---------- per-step attention + embedding: fills rnn_in and x_pred pieces
__global__ void __launch_bounds__(256) k_attn(const float* __restrict__ h_in,
        const float* __restrict__ attn_W, const float* __restrict__ attn_v,
        const float* __restrict__ Epre, const float* __restrict__ enc_bs,
        const float* __restrict__ dec_emb, const int* __restrict__ inp,
        float* __restrict__ rnn_in, float* __restrict__ x_pred){
    __shared__ float hrow[H_DIM];
    __shared__ float vs[D_DIM];
    __shared__ float hp[D_DIM];
    __shared__ float es[S_LEN];
    int b = blockIdx.x, tid = threadIdx.x;
    if (tid < 128){
        *(float4*)&hrow[tid<<2] = *(const float4*)(h_in + (long)b*H_DIM + (tid<<2));
        *(float4*)&vs[tid<<2]   = *(const float4*)(attn_v + (tid<<2));
    }
    __syncthreads();
    {   // hpart = h @ attn_W[0:512]
        float a0=0.f, a1=0.f;
        int d0 = tid, d1 = tid + 256;
        for (int k=0;k<H_DIM;k++){
            float hk = hrow[k];
            a0 += hk * attn_W[(long)k*D_DIM + d0];
            a1 += hk * attn_W[(long)k*D_DIM + d1];
        }
        hp[d0]=a0; hp[d1]=a1;
    }
    __syncthreads();
    int lane = tid & 63, w = tid >> 6;
    for (int si = 0; si < 16; ++si){
        int s = w*16 + si;
        const float* ep = Epre + ((long)b*S_LEN + s)*D_DIM;
        float sum = 0.f;
        #pragma unroll
        for (int q=0;q<8;q++){
            int d = lane + (q<<6);
            sum += tanhf(hp[d] + ep[d]) * vs[d];
        }
        #pragma unroll
        for (int m=32;m>0;m>>=1) sum += __shfl_xor(sum, m, 64);
        if (lane==0) es[s] = sum;
    }
    __syncthreads();
    if (tid < 64){
        float v = es[tid];
        float mx = v;
        #pragma unroll
        for (int m=32;m>0;m>>=1) mx = fmaxf(mx, __shfl_xor(mx, m, 64));
        float p = expf(v - mx);
        float sm = p;
        #pragma unroll
        for (int m=32;m>0;m>>=1) sm += __shfl_xor(sm, m, 64);
        es[tid] = p / sm;
    }
    __syncthreads();
    {   // weighted[j] = sum_s a[s]*enc_bs[b][s][j]
        float4 acc = make_float4(0.f,0.f,0.f,0.f);
        const float* eb = enc_bs + (long)b*S_LEN*H2 + (tid<<2);
        for (int s=0;s<S_LEN;s++){
            float a = es[s];
            float4 v = *(const float4*)(eb + (long)s*H2);
            acc.x += a*v.x; acc.y += a*v.y; acc.z += a*v.z; acc.w += a*v.w;
        }
        *(float4*)&rnn_in[(long)b*KDEC + E_DIM + (tid<<2)] = acc;
        *(float4*)&x_pred[(long)b*KPRED + D_DIM + (tid<<2)] = acc;
    }
    if (tid < 64){
        int tok = inp[b];
        float4 em = *(const float4*)(dec_emb + (long)tok*E_DIM + (tid<<2));
        *(float4*)&rnn_in[(long)b*KDEC + (tid<<2)] = em;
        *(float4*)&x_pred[(long)b*KPRED + D_DIM + H2 + (tid<<2)] = em;
    }
}

// ---------- decoder GRU step: h_out from rnn_in, h_in; also writes x_pred[0:512]
__global__ void __launch_bounds__(256) k_gru(const float* __restrict__ h_in,
        const float* __restrict__ Wih, const float* __restrict__ Whh,
        const float* __restrict__ bih, const float* __restrict__ bhh,
        const float* __restrict__ rnn_in, float* __restrict__ h_out,
        float* __restrict__ x_pred){
    __shared__ float ch[32*128];
    int tid = threadIdx.x;
    int b = tid & 31, jj = tid >> 5;
    int j = blockIdx.x*8 + jj;
    float air=0.f, aiz=0.f, ain=0.f;
    const float* wr = Wih + (long)j*KDEC;
    const float* wz = Wih + (long)(D_DIM + j)*KDEC;
    const float* wn = Wih + (long)(2*D_DIM + j)*KDEC;
    for (int kc=0;kc<10;kc++){
        __syncthreads();
        for (int e = tid; e < 1024; e += 256){
            int bb = e >> 5, kq = (e & 31) << 2;
            *(float4*)&ch[bb*128+kq] = *(const float4*)(rnn_in + (long)bb*KDEC + kc*128 + kq);
        }
        __syncthreads();
        const float* xrow = &ch[b*128];
        int kb = kc*128;
        #pragma unroll 8
        for (int kq=0;kq<128;kq+=4){
            float4 x4 = *(const float4*)&xrow[kq];
            float4 w;
            w = *(const float4*)&wr[kb+kq]; air += x4.x*w.x+x4.y*w.y+x4.z*w.z+x4.w*w.w;
            w = *(const float4*)&wz[kb+kq]; aiz += x4.x*w.x+x4.y*w.y+x4.z*w.z+x4.w*w.w;
            w = *(const float4*)&wn[kb+kq]; ain += x4.x*w.x+x4.y*w.y+x4.z*w.z+x4.w*w.w;
        }
    }
    float ahr=0.f, ahz=0.f, ahn=0.f;
    const float* vr = Whh + (long)j*D_DIM;
    const float* vz = Whh + (long)(D_DIM+j)*D_DIM;
    const float* vn = Whh + (long)(2*D_DIM+j)*D_DIM;
    for (int kc=0;kc<4;kc++){
        __syncthreads();
        for (int e = tid; e < 1024; e += 256){
            int bb = e >> 5, kq = (e & 31) << 2;
            *(float4*)&ch[bb*128+kq] = *(const float4*)(h_in + (long)bb*D_DIM + kc*128 + kq);
        }
        __syncthreads();
        const float* hrow = &ch[b*128];
        int kb = kc*128;
        #pragma unroll 8
        for (int kq=0;kq<128;kq+=4){
            float4 h4 = *(const float4*)&hrow[kq];
            float4 w;
            w = *(const float4*)&vr[kb+kq]; ahr += h4.x*w.x+h4.y*w.y+h4.z*w.z+h4.w*w.w;
            w = *(const float4*)&vz[kb+kq]; ahz += h4.x*w.x+h4.y*w.y+h4.z*w.z+h4.w*w.w;
            w = *(const float4*)&vn[kb+kq]; ahn += h4.x*w.x+h4.y*w.y+h4.z*w.z+h4.w*w.w;
        }
    }
    float r = sigmoidf_(air + bih[j] + ahr + bhh[j]);
    float z = sigmoidf_(aiz + bih[D_DIM+j] + ahz + bhh[D_DIM+j]);
    float n = tanhf(ain + bih[2*D_DIM+j] + r*(ahn + bhh[2*D_DIM+j]));
    float hv = h_in[(long)b*D_DIM + j];
    float hnew = (1.f - z)*n + z*hv;
    h_out[(long)b*D_DIM + j] = hnew;
    x_pred[(long)b*KPRED + j] = hnew;
}

// ---------- output projection: out[32, 32000] = x[32,1792] @ W[1792,32000] + out_b
__global__ void __launch_bounds__(512) k_pred(const float* __restrict__ x,
        const float* __restrict__ W, const float* __restrict__ bias,
        float* __restrict__ out){
    __shared__ float xs[16][32];
    __shared__ float Ws[16][128];
    int tid = threadIdx.x;
    int n0 = blockIdx.x * 128;
    int tm = tid >> 6;        // 0..7 -> rows tm*4..tm*4+3
    int tn = tid & 63;        // cols tn*2, tn*2+1
    float acc[4][2] = {{0}};
    for (int k0=0;k0<KPRED;k0+=16){
        __syncthreads();
        if (tid < 128){
            int row = tid >> 2, kq = (tid & 3) << 2;
            float4 v = *(const float4*)(x + (long)row*KPRED + k0 + kq);
            xs[kq+0][row]=v.x; xs[kq+1][row]=v.y; xs[kq+2][row]=v.z; xs[kq+3][row]=v.w;
        }
        {
            int kk = tid >> 5, nq = (tid & 31) << 2;
            *(float4*)&Ws[kk][nq] = *(const float4*)(W + (long)(k0+kk)*NV + n0 + nq);
        }
        __syncthreads();
        #pragma unroll
        for (int k=0;k<16;k++){
            float4 a4 = ((const float4*)xs[k])[tm];
            float2 w2 = ((const float2*)Ws[k])[tn];
            acc[0][0] += a4.x*w2.x; acc[0][1] += a4.x*w2.y;
            acc[1][0] += a4.y*w2.x; acc[1][1] += a4.y*w2.y;
            acc[2][0] += a4.z*w2.x; acc[2][1] += a4.z*w2.y;
            acc[3][0] += a4.w*w2.x; acc[3][1] += a4.w*w2.y;
        }
    }
    float b0 = bias[n0 + tn*2], b1 = bias[n0 + tn*2 + 1];
    #pragma unroll
    for (int i=0;i<4;i++){
        int m = tm*4 + i;
        float2 o = make_float2(acc[i][0] + b0, acc[i][1] + b1);
        *(float2*)(out + (long)m*NV + n0 + tn*2) = o;
    }
}

// ---------- argmax over vocab + next-input select
__global__ void __launch_bounds__(256) k_argmax(int step, const float* __restrict__ out_t,
        const int* __restrict__ trg, const int* __restrict__ tfm,
        int* __restrict__ inp){
    __shared__ float sv[256];
    __shared__ int   si[256];
    int b = blockIdx.x, tid = threadIdx.x;
    const float* row = out_t + (long)b*NV;
    float best = -INFINITY; int bi = 0;
    for (int j = tid; j < NV; j += 256){
        float v = row[j];
        if (v > best){ best = v; bi = j; }
    }
    sv[tid]=best; si[tid]=bi;
    __syncthreads();
    for (int s=128; s>0; s>>=1){
        if (tid < s){
            if (sv[tid+s] > sv[tid] || (sv[tid+s]==sv[tid] && si[tid+s] < si[tid])){
                sv[tid]=sv[tid+s]; si[tid]=si[tid+s];
            }
        }
        __syncthreads();
    }
    if (tid==0){
        inp[b] = (tfm[step+1] > 0) ? trg[(long)(step+1)*B_SZ + b] : si[0];
    }
}

extern "C" void kernel_launch(void* const* d_in, const int* in_sizes, int n_in,
                              void* d_out, int out_size, void* d_ws, size_t ws_size,
                              hipStream_t stream){
    const int*   src     = (const int*)d_in[0];
    const int*   trg     = (const int*)d_in[1];
    const int*   tfm     = (const int*)d_in[2];
    const float* enc_emb = (const float*)d_in[3];
    const float* Wih_f   = (const float*)d_in[4];
    const float* Whh_f   = (const float*)d_in[5];
    const float* bih_f   = (const float*)d_in[6];
    const float* bhh_f   = (const float*)d_in[7];
    const float* Wih_b   = (const float*)d_in[8];
    const float* Whh_b   = (const float*)d_in[9];
    const float* bih_b   = (const float*)d_in[10];
    const float* bhh_b   = (const float*)d_in[11];
    const float* Wfc     = (const float*)d_in[12];
    const float* bfc     = (const float*)d_in[13];
    const float* attn_W  = (const float*)d_in[14];
    const float* attn_b  = (const float*)d_in[15];
    const float* attn_v  = (const float*)d_in[16];
    const float* dec_emb = (const float*)d_in[17];
    const float* dWih    = (const float*)d_in[18];
    const float* dWhh    = (const float*)d_in[19];
    const float* dbih    = (const float*)d_in[20];
    const float* dbhh    = (const float*)d_in[21];
    const float* out_W   = (const float*)d_in[22];
    const float* out_b   = (const float*)d_in[23];
    float* out = (float*)d_out;

    // workspace layout (floats), with overlays:
    //   emb_src [524288] | gi_f [3145728] | gi_b [3145728] | outs_f [1048576] | outs_b [1048576]
    //   after encoder: gi_f region -> enc_bs(2097152)+Epre(1048576); gi_b region -> decoder state
    float* ws      = (float*)d_ws;
    float* emb_src = ws;
    float* gi_f    = emb_src + 524288;
    float* gi_b    = gi_f + 3145728;
    float* outs_f  = gi_b + 3145728;
    float* outs_b  = outs_f + 1048576;
    // overlays
    float* enc_bs  = gi_f;
    float* Epre    = gi_f + 2097152;
    float* h0      = gi_b;
    float* h1      = h0 + 16384;
    float* rnn_in  = h1 + 16384;
    float* x_pred  = rnn_in + 40960;
    int*   inp     = (int*)(x_pred + 57344);

    // out[0] must be zeros (harness poisons d_out each run)
    hipMemsetAsync(d_out, 0, (size_t)B_SZ*NV*sizeof(float), stream);

    k_embed<<<512,256,0,stream>>>(src, enc_emb, emb_src);
    // gi for all timesteps, both directions (natural order; backward indexes reversed)
    k_gemm64<1><<<(2048/64)*(G3H/64),256,0,stream>>>(emb_src, Wih_f, bih_f, gi_f, 2048, G3H, E_DIM);
    k_gemm64<1><<<(2048/64)*(G3H/64),256,0,stream>>>(emb_src, Wih_b, bih_b, gi_b, 2048, G3H, E_DIM);
    for (int t=0;t<S_LEN;t++)
        k_enc_step<<<64,256,0,stream>>>(t, gi_f, gi_b, Whh_f, Whh_b, bhh_f, bhh_b, outs_f, outs_b);
    k_encbs<<<2048,256,0,stream>>>(outs_f, outs_b, enc_bs);
    k_hidden<<<64,256,0,stream>>>(outs_f, outs_b, Wfc, bfc, trg, h0, inp);
    // Epre = enc_bs @ attn_W[512:,:] + attn_b
    k_gemm64<0><<<(2048/64)*(D_DIM/64),256,0,stream>>>(enc_bs, attn_W + (long)D_DIM*D_DIM, attn_b,
                                                       Epre, 2048, D_DIM, H2);
    float* hbuf[2] = {h0, h1};
    for (int i=0;i<T_LEN-1;i++){
        float* hin  = hbuf[i&1];
        float* hout = hbuf[(i+1)&1];
        float* out_t = out + (size_t)(i+1)*B_SZ*NV;
        k_attn<<<32,256,0,stream>>>(hin, attn_W, attn_v, Epre, enc_bs, dec_emb, inp, rnn_in, x_pred);
        k_gru<<<64,256,0,stream>>>(hin, dWih, dWhh, dbih, dbhh, rnn_in, hout, x_pred);
        k_pred<<<NV/128,512,0,stream>>>(x_pred, out_W, out_b, out_t);
        k_argmax<<<32,256,0,stream>>>(i, out_t, trg, tfm, inp);
    }
}

// Round 3
// 11264.603 us; speedup vs baseline: 1.7493x; 1.7493x over previous
//
#include <hip/hip_runtime.h>
#include <math.h>

#define S_LEN 64
#define T_LEN 48
#define B_SZ  32
#define NV    32000
#define E_DIM 256
#define H_DIM 512
#define D_DIM 512
#define H2    1024          // 2H
#define G3H   1536          // 3H == 3D
#define KDEC  1280          // E + 2H
#define KPRED 1792          // D + 2H + E

typedef __attribute__((ext_vector_type(8)))  short short8v;
typedef __attribute__((ext_vector_type(16))) float f32x16;

__device__ __forceinline__ float fsig_(float x){ return 1.0f/(1.0f + __expf(-x)); }
__device__ __forceinline__ float ftanh_(float x){ return 1.0f - 2.0f/(__expf(2.0f*x) + 1.0f); }

// split fp32 into hi/lo bf16 (truncation; lo = exact residual then truncated)
__device__ __forceinline__ void split2(float f, unsigned short& h, unsigned short& l){
    unsigned u  = __float_as_uint(f);
    unsigned hu = u & 0xFFFF0000u;
    h = (unsigned short)(hu >> 16);
    float lo = f - __uint_as_float(hu);
    l = (unsigned short)(__float_as_uint(lo) >> 16);
}

// ---------- encoder embedding gather
__global__ void k_embed(const int* __restrict__ src, const float* __restrict__ enc_emb,
                        float* __restrict__ emb_src){
    int idx = blockIdx.x*256 + threadIdx.x;
    int e4 = idx & 63;
    int r  = idx >> 6;
    int tok = src[r];
    ((float4*)emb_src)[idx] = ((const float4*)(enc_emb + (long)tok*E_DIM))[e4];
}

// ---------- generic 64x64 tiled fp32 GEMM.  C = A @ op(W) + bias
template<int BT>
__global__ void __launch_bounds__(256) k_gemm64(const float* __restrict__ A,
        const float* __restrict__ W, const float* __restrict__ bias,
        float* __restrict__ C, int M, int N, int K){
    __shared__ float As[16][64];
    __shared__ float Bs[16][64];
    int ntile = N >> 6;
    int m0 = (blockIdx.x / ntile) << 6;
    int n0 = (blockIdx.x % ntile) << 6;
    int tid = threadIdx.x;
    int tm = tid >> 4, tn = tid & 15;
    float acc[4][4] = {{0}};
    for (int k0 = 0; k0 < K; k0 += 16){
        __syncthreads();
        {
            int row = tid >> 2, kq = (tid & 3) << 2;
            float4 v = *(const float4*)(A + (long)(m0+row)*K + k0 + kq);
            As[kq+0][row]=v.x; As[kq+1][row]=v.y; As[kq+2][row]=v.z; As[kq+3][row]=v.w;
        }
        if (BT){
            int row = tid >> 2, kq = (tid & 3) << 2;
            float4 v = *(const float4*)(W + (long)(n0+row)*K + k0 + kq);
            Bs[kq+0][row]=v.x; Bs[kq+1][row]=v.y; Bs[kq+2][row]=v.z; Bs[kq+3][row]=v.w;
        } else {
            int kk = tid >> 4, nq = (tid & 15) << 2;
            *(float4*)&Bs[kk][nq] = *(const float4*)(W + (long)(k0+kk)*N + n0 + nq);
        }
        __syncthreads();
        #pragma unroll
        for (int k = 0; k < 16; ++k){
            float4 a4 = ((const float4*)As[k])[tm];
            float4 b4 = ((const float4*)Bs[k])[tn];
            float av[4] = {a4.x,a4.y,a4.z,a4.w};
            float bv[4] = {b4.x,b4.y,b4.z,b4.w};
            #pragma unroll
            for (int i=0;i<4;++i)
                #pragma unroll
                for (int j=0;j<4;++j)
                    acc[i][j] += av[i]*bv[j];
        }
    }
    int n = n0 + (tn<<2);
    float b0=bias[n], b1=bias[n+1], b2=bias[n+2], b3=bias[n+3];
    #pragma unroll
    for (int i=0;i<4;++i){
        int m = m0 + (tm<<2) + i;
        float4 o = make_float4(acc[i][0]+b0, acc[i][1]+b1, acc[i][2]+b2, acc[i][3]+b3);
        *(float4*)(C + (long)m*N + n) = o;
    }
}

// ---------- one encoder timestep, both directions fused
__global__ void __launch_bounds__(256) k_enc_step(int t,
        const float* __restrict__ gi_f, const float* __restrict__ gi_b,
        const float* __restrict__ Whh_f, const float* __restrict__ Whh_b,
        const float* __restrict__ bhh_f, const float* __restrict__ bhh_b,
        float* __restrict__ outs_f, float* __restrict__ outs_b){
    __shared__ float ch[32*128];
    int dir  = blockIdx.x >> 5;
    int jblk = blockIdx.x & 31;
    int j0 = jblk << 4;
    int tid = threadIdx.x;
    int b = tid & 31, jj = tid >> 5;
    const float* gi   = dir ? gi_b  : gi_f;
    const float* Whh  = dir ? Whh_b : Whh_f;
    const float* bhh  = dir ? bhh_b : bhh_f;
    float*       outs = dir ? outs_b : outs_f;
    const float* hprev = (t > 0) ? (outs + (long)(t-1)*B_SZ*H_DIM) : nullptr;
    int ja = j0 + jj, jb = j0 + 8 + jj;
    float hr0=0,hz0=0,hn0=0, hr1=0,hz1=0,hn1=0;
    for (int kc = 0; kc < 4; ++kc){
        __syncthreads();
        for (int e = tid; e < 1024; e += 256){
            int bb = e >> 5, kq = (e & 31) << 2;
            float4 v = hprev ? *(const float4*)(hprev + bb*H_DIM + kc*128 + kq)
                             : make_float4(0.f,0.f,0.f,0.f);
            *(float4*)&ch[bb*128 + kq] = v;
        }
        __syncthreads();
        const float* wra = Whh + (long)ja*H_DIM + kc*128;
        const float* wza = Whh + (long)(H_DIM + ja)*H_DIM + kc*128;
        const float* wna = Whh + (long)(2*H_DIM + ja)*H_DIM + kc*128;
        const float* wrb = Whh + (long)jb*H_DIM + kc*128;
        const float* wzb = Whh + (long)(H_DIM + jb)*H_DIM + kc*128;
        const float* wnb = Whh + (long)(2*H_DIM + jb)*H_DIM + kc*128;
        const float* hrow = &ch[b*128];
        #pragma unroll 8
        for (int kq = 0; kq < 128; kq += 4){
            float4 h4 = *(const float4*)&hrow[kq];
            float4 w;
            w = *(const float4*)&wra[kq]; hr0 += h4.x*w.x+h4.y*w.y+h4.z*w.z+h4.w*w.w;
            w = *(const float4*)&wza[kq]; hz0 += h4.x*w.x+h4.y*w.y+h4.z*w.z+h4.w*w.w;
            w = *(const float4*)&wna[kq]; hn0 += h4.x*w.x+h4.y*w.y+h4.z*w.z+h4.w*w.w;
            w = *(const float4*)&wrb[kq]; hr1 += h4.x*w.x+h4.y*w.y+h4.z*w.z+h4.w*w.w;
            w = *(const float4*)&wzb[kq]; hz1 += h4.x*w.x+h4.y*w.y+h4.z*w.z+h4.w*w.w;
            w = *(const float4*)&wnb[kq]; hn1 += h4.x*w.x+h4.y*w.y+h4.z*w.z+h4.w*w.w;
        }
    }
    int gidx = dir ? (S_LEN-1-t) : t;
    long gbase = (long)gidx*B_SZ*G3H + (long)b*G3H;
    float* orow = outs + (long)t*B_SZ*H_DIM + (long)b*H_DIM;
    {
        float r = fsig_(gi[gbase + ja] + hr0 + bhh[ja]);
        float z = fsig_(gi[gbase + H_DIM + ja] + hz0 + bhh[H_DIM + ja]);
        float n = ftanh_(gi[gbase + 2*H_DIM + ja] + r*(hn0 + bhh[2*H_DIM + ja]));
        float hv = (t>0) ? hprev[b*H_DIM + ja] : 0.f;
        orow[ja] = (1.f - z)*n + z*hv;
    }
    {
        float r = fsig_(gi[gbase + jb] + hr1 + bhh[jb]);
        float z = fsig_(gi[gbase + H_DIM + jb] + hz1 + bhh[H_DIM + jb]);
        float n = ftanh_(gi[gbase + 2*H_DIM + jb] + r*(hn1 + bhh[2*H_DIM + jb]));
        float hv = (t>0) ? hprev[b*H_DIM + jb] : 0.f;
        orow[jb] = (1.f - z)*n + z*hv;
    }
}

// ---------- assemble enc_bs[b][s][:] = [outs_f[s][b] | outs_b[S-1-s][b]]
__global__ void k_encbs(const float* __restrict__ outs_f, const float* __restrict__ outs_b,
                        float* __restrict__ enc_bs){
    int idx = blockIdx.x*256 + threadIdx.x;
    int j4 = idx & 255;
    int r  = idx >> 8;
    int s = r & 63, b = r >> 6;
    float4 v;
    if (j4 < 128) v = *(const float4*)(outs_f + ((long)s*B_SZ + b)*H_DIM + (j4<<2));
    else          v = *(const float4*)(outs_b + ((long)(S_LEN-1-s)*B_SZ + b)*H_DIM + ((j4-128)<<2));
    ((float4*)enc_bs)[idx] = v;
}

// ---------- hidden = tanh([h_f|h_b] @ Wfc + bfc); init inp = trg[0]
__global__ void k_hidden(const float* __restrict__ outs_f, const float* __restrict__ outs_b,
                         const float* __restrict__ Wfc, const float* __restrict__ bfc,
                         const int* __restrict__ trg, float* __restrict__ h0,
                         int* __restrict__ inp){
    int idx = blockIdx.x*256 + threadIdx.x;
    int b = idx >> 9, d = idx & 511;
    const float* af = outs_f + (long)(S_LEN-1)*B_SZ*H_DIM + (long)b*H_DIM;
    const float* ab = outs_b + (long)(S_LEN-1)*B_SZ*H_DIM + (long)b*H_DIM;
    float acc = bfc[d];
    for (int k=0;k<H_DIM;k++) acc += af[k]*Wfc[(long)k*D_DIM + d];
    for (int k=0;k<H_DIM;k++) acc += ab[k]*Wfc[(long)(H_DIM+k)*D_DIM + d];
    h0[idx] = ftanh_(acc);
    if (idx < B_SZ) inp[idx] = trg[idx];
}

// ---------- per-step attention + embedding (512 threads, split-K hpart)
__global__ void __launch_bounds__(512) k_attn(const float* __restrict__ h_in,
        const float* __restrict__ attn_W, const float* __restrict__ attn_v,
        const float* __restrict__ Epre, const float* __restrict__ enc_bs,
        const float* __restrict__ dec_emb, const int* __restrict__ inp,
        float* __restrict__ rnn_in, float* __restrict__ x_pred){
    __shared__ float hrow[D_DIM];
    __shared__ float vs[D_DIM];
    __shared__ float hpp[4*D_DIM];
    __shared__ float hp[D_DIM];
    __shared__ float es[S_LEN];
    __shared__ float wpart[2][H2];
    int b = blockIdx.x, tid = threadIdx.x;
    if (tid < 128)      *(float4*)&hrow[tid<<2]       = *(const float4*)(h_in + (long)b*H_DIM + (tid<<2));
    else if (tid < 256) *(float4*)&vs[(tid-128)<<2]   = *(const float4*)(attn_v + ((tid-128)<<2));
    __syncthreads();
    {   // hpart = h @ attn_W[0:512], split over 4 k-slices of 128
        int cg = tid & 127, ks = tid >> 7;
        float4 a4 = make_float4(0.f,0.f,0.f,0.f);
        const float* wp = attn_W + (long)(ks*128)*D_DIM + (cg<<2);
        #pragma unroll 4
        for (int k = 0; k < 128; ++k){
            float hk = hrow[ks*128 + k];
            float4 w4 = *(const float4*)(wp + (long)k*D_DIM);
            a4.x += hk*w4.x; a4.y += hk*w4.y; a4.z += hk*w4.z; a4.w += hk*w4.w;
        }
        *(float4*)&hpp[ks*D_DIM + (cg<<2)] = a4;
    }
    __syncthreads();
    hp[tid] = hpp[tid] + hpp[D_DIM+tid] + hpp[2*D_DIM+tid] + hpp[3*D_DIM+tid];
    __syncthreads();
    int lane = tid & 63, w = tid >> 6;   // 8 waves
    #pragma unroll
    for (int si = 0; si < 8; ++si){
        int s = w*8 + si;
        const float* ep = Epre + ((long)b*S_LEN + s)*D_DIM;
        float sum = 0.f;
        #pragma unroll
        for (int q=0;q<8;q++){
            int d = lane + (q<<6);
            sum += ftanh_(hp[d] + ep[d]) * vs[d];
        }
        #pragma unroll
        for (int m=32;m>0;m>>=1) sum += __shfl_xor(sum, m, 64);
        if (lane==0) es[s] = sum;
    }
    __syncthreads();
    if (tid < 64){
        float v = es[tid];
        float mx = v;
        #pragma unroll
        for (int m=32;m>0;m>>=1) mx = fmaxf(mx, __shfl_xor(mx, m, 64));
        float p = __expf(v - mx);
        float sm = p;
        #pragma unroll
        for (int m=32;m>0;m>>=1) sm += __shfl_xor(sm, m, 64);
        es[tid] = p / sm;
    }
    __syncthreads();
    {   // weighted, split over 2 s-halves
        int c4 = tid & 255, half = tid >> 8;
        float4 acc = make_float4(0.f,0.f,0.f,0.f);
        const float* eb = enc_bs + (long)b*S_LEN*H2 + (c4<<2);
        for (int s = half*32; s < half*32+32; ++s){
            float a = es[s];
            float4 v = *(const float4*)(eb + (long)s*H2);
            acc.x += a*v.x; acc.y += a*v.y; acc.z += a*v.z; acc.w += a*v.w;
        }
        *(float4*)&wpart[half][c4<<2] = acc;
    }
    __syncthreads();
    if (tid < 256){
        float4 p0 = *(float4*)&wpart[0][tid<<2];
        float4 p1 = *(float4*)&wpart[1][tid<<2];
        float4 o = make_float4(p0.x+p1.x, p0.y+p1.y, p0.z+p1.z, p0.w+p1.w);
        *(float4*)&rnn_in[(long)b*KDEC + E_DIM + (tid<<2)] = o;
        *(float4*)&x_pred[(long)b*KPRED + D_DIM + (tid<<2)] = o;
    }
    if (tid < 64){
        int tok = inp[b];
        float4 em = *(const float4*)(dec_emb + (long)tok*E_DIM + (tid<<2));
        *(float4*)&rnn_in[(long)b*KDEC + (tid<<2)] = em;
        *(float4*)&x_pred[(long)b*KPRED + D_DIM + H2 + (tid<<2)] = em;
    }
}

// ---------- decoder GRU step
__global__ void __launch_bounds__(256) k_gru(const float* __restrict__ h_in,
        const float* __restrict__ Wih, const float* __restrict__ Whh,
        const float* __restrict__ bih, const float* __restrict__ bhh,
        const float* __restrict__ rnn_in, float* __restrict__ h_out,
        float* __restrict__ x_pred){
    __shared__ float ch[32*128];
    int tid = threadIdx.x;
    int b = tid & 31, jj = tid >> 5;
    int j = blockIdx.x*8 + jj;
    float air=0.f, aiz=0.f, ain=0.f;
    const float* wr = Wih + (long)j*KDEC;
    const float* wz = Wih + (long)(D_DIM + j)*KDEC;
    const float* wn = Wih + (long)(2*D_DIM + j)*KDEC;
    for (int kc=0;kc<10;kc++){
        __syncthreads();
        for (int e = tid; e < 1024; e += 256){
            int bb = e >> 5, kq = (e & 31) << 2;
            *(float4*)&ch[bb*128+kq] = *(const float4*)(rnn_in + (long)bb*KDEC + kc*128 + kq);
        }
        __syncthreads();
        const float* xrow = &ch[b*128];
        int kb = kc*128;
        #pragma unroll 8
        for (int kq=0;kq<128;kq+=4){
            float4 x4 = *(const float4*)&xrow[kq];
            float4 w;
            w = *(const float4*)&wr[kb+kq]; air += x4.x*w.x+x4.y*w.y+x4.z*w.z+x4.w*w.w;
            w = *(const float4*)&wz[kb+kq]; aiz += x4.x*w.x+x4.y*w.y+x4.z*w.z+x4.w*w.w;
            w = *(const float4*)&wn[kb+kq]; ain += x4.x*w.x+x4.y*w.y+x4.z*w.z+x4.w*w.w;
        }
    }
    float ahr=0.f, ahz=0.f, ahn=0.f;
    const float* vr = Whh + (long)j*D_DIM;
    const float* vz = Whh + (long)(D_DIM+j)*D_DIM;
    const float* vn = Whh + (long)(2*D_DIM+j)*D_DIM;
    for (int kc=0;kc<4;kc++){
        __syncthreads();
        for (int e = tid; e < 1024; e += 256){
            int bb = e >> 5, kq = (e & 31) << 2;
            *(float4*)&ch[bb*128+kq] = *(const float4*)(h_in + (long)bb*D_DIM + kc*128 + kq);
        }
        __syncthreads();
        const float* hrow = &ch[b*128];
        int kb = kc*128;
        #pragma unroll 8
        for (int kq=0;kq<128;kq+=4){
            float4 h4 = *(const float4*)&hrow[kq];
            float4 w;
            w = *(const float4*)&vr[kb+kq]; ahr += h4.x*w.x+h4.y*w.y+h4.z*w.z+h4.w*w.w;
            w = *(const float4*)&vz[kb+kq]; ahz += h4.x*w.x+h4.y*w.y+h4.z*w.z+h4.w*w.w;
            w = *(const float4*)&vn[kb+kq]; ahn += h4.x*w.x+h4.y*w.y+h4.z*w.z+h4.w*w.w;
        }
    }
    float r = fsig_(air + bih[j] + ahr + bhh[j]);
    float z = fsig_(aiz + bih[D_DIM+j] + ahz + bhh[D_DIM+j]);
    float n = ftanh_(ain + bih[2*D_DIM+j] + r*(ahn + bhh[2*D_DIM+j]));
    float hv = h_in[(long)b*D_DIM + j];
    float hnew = (1.f - z)*n + z*hv;
    h_out[(long)b*D_DIM + j] = hnew;
    x_pred[(long)b*KPRED + j] = hnew;
}

// ---------- bf16x3 MFMA output projection ---------------------------------
// C[32,32000] = x[32,1792] @ W[1792,32000] + b.  Per block: 128 cols, 4 waves
// each owning one 32x32 MFMA tile.  Frag buffers stored in lane-linear
// fragment order (conflict-free b128), double-buffered, reg-prefetch.
struct PredStage { float bv[16]; float4 av; };

__device__ __forceinline__ void pred_load(PredStage& st, const float* __restrict__ W,
        const float* __restrict__ x, int k0, int n0, int tid){
    int n = tid & 127, kgb = tid >> 7;           // kgb 0..1 -> kg {kgb, kgb+2}
    const float* wp0 = W + (size_t)(k0 + kgb*8)*NV + n0 + n;
    const float* wp1 = W + (size_t)(k0 + (kgb+2)*8)*NV + n0 + n;
    #pragma unroll
    for (int i=0;i<8;i++){ st.bv[i] = wp0[(size_t)i*NV]; st.bv[8+i] = wp1[(size_t)i*NV]; }
    int row = tid>>3, kq4 = (tid&7)<<2;
    st.av = *(const float4*)(x + (size_t)row*KPRED + k0 + kq4);
}

__device__ __forceinline__ void pred_store(const PredStage& st, int tid,
        unsigned short* Bh, unsigned short* Bl, unsigned short* Ah, unsigned short* Al){
    int n = tid & 127, kgb = tid >> 7;
    #pragma unroll
    for (int g=0; g<2; ++g){
        int kg = kgb + g*2;
        int off = (((kg>>1)*4 + (n>>5))*64 + (kg&1)*32 + (n&31)) * 8;
        unsigned hx[4], lx[4];
        #pragma unroll
        for (int p=0;p<4;p++){
            unsigned short h0,l0,h1,l1;
            split2(st.bv[g*8+2*p],   h0, l0);
            split2(st.bv[g*8+2*p+1], h1, l1);
            hx[p] = (unsigned)h0 | ((unsigned)h1<<16);
            lx[p] = (unsigned)l0 | ((unsigned)l1<<16);
        }
        *(uint4*)&Bh[off] = make_uint4(hx[0],hx[1],hx[2],hx[3]);
        *(uint4*)&Bl[off] = make_uint4(lx[0],lx[1],lx[2],lx[3]);
    }
    int row = tid>>3, kq4 = (tid&7)<<2;
    int slot = (kq4>>4)*64 + ((kq4>>3)&1)*32 + row;
    unsigned short h0,l0,h1,l1;
    unsigned ah0, ah1, al0, al1;
    split2(st.av.x,h0,l0); split2(st.av.y,h1,l1);
    ah0 = (unsigned)h0|((unsigned)h1<<16); al0 = (unsigned)l0|((unsigned)l1<<16);
    split2(st.av.z,h0,l0); split2(st.av.w,h1,l1);
    ah1 = (unsigned)h0|((unsigned)h1<<16); al1 = (unsigned)l0|((unsigned)l1<<16);
    *(uint2*)&Ah[slot*8 + (kq4&7)] = make_uint2(ah0, ah1);
    *(uint2*)&Al[slot*8 + (kq4&7)] = make_uint2(al0, al1);
}

__global__ void __launch_bounds__(256) k_pred_mfma(const float* __restrict__ x,
        const float* __restrict__ W, const float* __restrict__ bias,
        float* __restrict__ out){
    __shared__ __align__(16) unsigned short Bh[2][4096], Bl[2][4096];
    __shared__ __align__(16) unsigned short Ah[2][1024], Al[2][1024];
    int tid = threadIdx.x;
    int n0 = blockIdx.x * 128;
    int w = tid >> 6, lane = tid & 63;
    PredStage st;
    pred_load(st, W, x, 0, n0, tid);
    pred_store(st, tid, Bh[0], Bl[0], Ah[0], Al[0]);
    __syncthreads();
    f32x16 acc_hh = (f32x16)(0.0f);
    f32x16 acc_lh = (f32x16)(0.0f);
    f32x16 acc_hl = (f32x16)(0.0f);
    for (int c = 0; c < 56; ++c){
        int cur = c & 1;
        if (c < 55) pred_load(st, W, x, (c+1)*32, n0, tid);
        #pragma unroll
        for (int kh=0; kh<2; ++kh){
            short8v ahf = *(short8v*)&Ah[cur][(kh*64+lane)*8];
            short8v alf = *(short8v*)&Al[cur][(kh*64+lane)*8];
            short8v bhf = *(short8v*)&Bh[cur][((kh*4+w)*64+lane)*8];
            short8v blf = *(short8v*)&Bl[cur][((kh*4+w)*64+lane)*8];
            acc_hh = __builtin_amdgcn_mfma_f32_32x32x16_bf16(ahf, bhf, acc_hh, 0,0,0);
            acc_lh = __builtin_amdgcn_mfma_f32_32x32x16_bf16(alf, bhf, acc_lh, 0,0,0);
            acc_hl = __builtin_amdgcn_mfma_f32_32x32x16_bf16(ahf, blf, acc_hl, 0,0,0);
        }
        if (c < 55){
            pred_store(st, tid, Bh[cur^1], Bl[cur^1], Ah[cur^1], Al[cur^1]);
            __syncthreads();
        }
    }
    int col = n0 + w*32 + (lane & 31);
    float bv = bias[col];
    #pragma unroll
    for (int i=0;i<16;i++){
        int row = (i&3) + 8*(i>>2) + 4*(lane>>5);
        out[(size_t)row*NV + col] = acc_hh[i] + acc_lh[i] + acc_hl[i] + bv;
    }
}

// ---------- argmax over vocab + next-input select (float4 loads)
__global__ void __launch_bounds__(256) k_argmax(int step, const float* __restrict__ out_t,
        const int* __restrict__ trg, const int* __restrict__ tfm,
        int* __restrict__ inp){
    __shared__ float sv[256];
    __shared__ int   si[256];
    int b = blockIdx.x, tid = threadIdx.x;
    const float4* row4 = (const float4*)(out_t + (long)b*NV);
    float best = -INFINITY; int bi = 0;
    for (int j4 = tid; j4 < NV/4; j4 += 256){
        float4 v = row4[j4];
        int base = j4 << 2;
        if (v.x > best){ best = v.x; bi = base;   }
        if (v.y > best){ best = v.y; bi = base+1; }
        if (v.z > best){ best = v.z; bi = base+2; }
        if (v.w > best){ best = v.w; bi = base+3; }
    }
    sv[tid]=best; si[tid]=bi;
    __syncthreads();
    for (int s=128; s>0; s>>=1){
        if (tid < s){
            if (sv[tid+s] > sv[tid] || (sv[tid+s]==sv[tid] && si[tid+s] < si[tid])){
                sv[tid]=sv[tid+s]; si[tid]=si[tid+s];
            }
        }
        __syncthreads();
    }
    if (tid==0){
        inp[b] = (tfm[step+1] > 0) ? trg[(long)(step+1)*B_SZ + b] : si[0];
    }
}

extern "C" void kernel_launch(void* const* d_in, const int* in_sizes, int n_in,
                              void* d_out, int out_size, void* d_ws, size_t ws_size,
                              hipStream_t stream){
    const int*   src     = (const int*)d_in[0];
    const int*   trg     = (const int*)d_in[1];
    const int*   tfm     = (const int*)d_in[2];
    const float* enc_emb = (const float*)d_in[3];
    const float* Wih_f   = (const float*)d_in[4];
    const float* Whh_f   = (const float*)d_in[5];
    const float* bih_f   = (const float*)d_in[6];
    const float* bhh_f   = (const float*)d_in[7];
    const float* Wih_b   = (const float*)d_in[8];
    const float* Whh_b   = (const float*)d_in[9];
    const float* bih_b   = (const float*)d_in[10];
    const float* bhh_b   = (const float*)d_in[11];
    const float* Wfc     = (const float*)d_in[12];
    const float* bfc     = (const float*)d_in[13];
    const float* attn_W  = (const float*)d_in[14];
    const float* attn_b  = (const float*)d_in[15];
    const float* attn_v  = (const float*)d_in[16];
    const float* dec_emb = (const float*)d_in[17];
    const float* dWih    = (const float*)d_in[18];
    const float* dWhh    = (const float*)d_in[19];
    const float* dbih    = (const float*)d_in[20];
    const float* dbhh    = (const float*)d_in[21];
    const float* out_W   = (const float*)d_in[22];
    const float* out_b   = (const float*)d_in[23];
    float* out = (float*)d_out;

    float* ws      = (float*)d_ws;
    float* emb_src = ws;
    float* gi_f    = emb_src + 524288;
    float* gi_b    = gi_f + 3145728;
    float* outs_f  = gi_b + 3145728;
    float* outs_b  = outs_f + 1048576;
    // overlays after encoder
    float* enc_bs  = gi_f;
    float* Epre    = gi_f + 2097152;
    float* h0      = gi_b;
    float* h1      = h0 + 16384;
    float* rnn_in  = h1 + 16384;
    float* x_pred  = rnn_in + 40960;
    int*   inp     = (int*)(x_pred + 57344);

    hipMemsetAsync(d_out, 0, (size_t)B_SZ*NV*sizeof(float), stream);

    k_embed<<<512,256,0,stream>>>(src, enc_emb, emb_src);
    k_gemm64<1><<<(2048/64)*(G3H/64),256,0,stream>>>(emb_src, Wih_f, bih_f, gi_f, 2048, G3H, E_DIM);
    k_gemm64<1><<<(2048/64)*(G3H/64),256,0,stream>>>(emb_src, Wih_b, bih_b, gi_b, 2048, G3H, E_DIM);
    for (int t=0;t<S_LEN;t++)
        k_enc_step<<<64,256,0,stream>>>(t, gi_f, gi_b, Whh_f, Whh_b, bhh_f, bhh_b, outs_f, outs_b);
    k_encbs<<<2048,256,0,stream>>>(outs_f, outs_b, enc_bs);
    k_hidden<<<64,256,0,stream>>>(outs_f, outs_b, Wfc, bfc, trg, h0, inp);
    k_gemm64<0><<<(2048/64)*(D_DIM/64),256,0,stream>>>(enc_bs, attn_W + (long)D_DIM*D_DIM, attn_b,
                                                       Epre, 2048, D_DIM, H2);
    float* hbuf[2] = {h0, h1};
    for (int i=0;i<T_LEN-1;i++){
        float* hin  = hbuf[i&1];
        float* hout = hbuf[(i+1)&1];
        float* out_t = out + (size_t)(i+1)*B_SZ*NV;
        k_attn<<<32,512,0,stream>>>(hin, attn_W, attn_v, Epre, enc_bs, dec_emb, inp, rnn_in, x_pred);
        k_gru<<<64,256,0,stream>>>(hin, dWih, dWhh, dbih, dbhh, rnn_in, hout, x_pred);
        k_pred_mfma<<<NV/128,256,0,stream>>>(x_pred, out_W, out_b, out_t);
        k_argmax<<<32,256,0,stream>>>(i, out_t, trg, tfm, inp);
    }
}